// Round 15
// baseline (167.177 us; speedup 1.0000x reference)
//
#include <hip/hip_runtime.h>
#include <hip/hip_bf16.h>

// GCN layer: out = segment_sum(edge_val * (x@W)[col], row) + bias
// N=100000 nodes, E=640000 edges, D=128.
// y bf16. Pipeline: memset(ctrl) -> fused{partition(blocks<157 first) ||
// ticket-balanced MFMA gemm(all 512 blocks)} -> LDS-built ELL ->
// spmm (4 nodes/wave, uint4 gathers) -> overflow fixup.

#define N_NODES 100000
#define N_EDGES 640000
#define D 128
#define ELL_K 16
#define OVF_CAP 8192
#define NB 391          // ceil(N_NODES/256) row buckets
#define BCAP 2048       // per-bucket edge capacity (avg 1638)
#define CHUNK 4096
#define NCHUNKS 157     // ceil(N_EDGES/CHUNK)
#define N_TILES 6250
#define YT_P 132        // padded node-row stride in ushorts (banks spread)
#define GRID 512        // all co-resident (2 blk/CU by VGPR, <=3 by LDS)

typedef __attribute__((ext_vector_type(8))) short short8;
typedef __attribute__((ext_vector_type(4))) float f32x4;
typedef __attribute__((ext_vector_type(4))) ushort us4;

__device__ __forceinline__ ushort f2bf(float f) {
    __hip_bfloat16 h = __float2bfloat16(f);
    return __builtin_bit_cast(ushort, h);
}
__device__ __forceinline__ float bflo(uint u) { return __uint_as_float(u << 16); }
__device__ __forceinline__ float bfhi(uint u) { return __uint_as_float(u & 0xffff0000u); }

// ---- fused: edge partition (blocks < NCHUNKS, runs FIRST so it overlaps
// gemm on the other blocks) + ticket-balanced MFMA gemm (ALL blocks) -------
// gemm: W^T in LDS (XOR-swizzled) -> 8x4 B-fragments in regs; swapped mfma;
// coalesced epilogue via per-wave padded LDS tile. Tile index from a global
// ticket: the atomic is ISSUED before the MFMA block and CONSUMED (shfl)
// after it, hiding the agent-atomic latency under compute.
// ctrl: [0]=tick, [1]=ovfCnt, [2..]=bucketCnt  (memset to 0 pre-launch)
__global__ __launch_bounds__(256, 2) void gemm_part(const float* __restrict__ x,
                                                    const float* __restrict__ w,
                                                    ushort* __restrict__ y,
                                                    const float* __restrict__ ev,
                                                    const int* __restrict__ row,
                                                    const int* __restrict__ col,
                                                    uint2* __restrict__ es0,
                                                    int* __restrict__ ctrl,
                                                    int* __restrict__ ovfRow,
                                                    int* __restrict__ ovfCol,
                                                    float* __restrict__ ovfVal) {
    __shared__ union {
        struct { ushort wt[128 * 128]; ushort ytile[4][16 * YT_P]; } g;  // 48.5KB
        struct { int hist[NB]; int cur[NB]; } p;                          // 3.1KB
    } sm;
    const int tid = threadIdx.x;
    int* tick = ctrl + 0;
    int* ovfCnt = ctrl + 1;
    int* bucketCnt = ctrl + 2;

    // ---------------- partition role (blocks < NCHUNKS), FIRST -----------
    if (blockIdx.x < NCHUNKS) {
        const int base = blockIdx.x * CHUNK;
        for (int t = tid; t < NB; t += 256) sm.p.hist[t] = 0;
        __syncthreads();
        #pragma unroll
        for (int it = 0; it < CHUNK / 256; ++it) {
            int i = base + it * 256 + tid;
            if (i < N_EDGES) atomicAdd(&sm.p.hist[row[i] >> 8], 1);
        }
        __syncthreads();
        for (int t = tid; t < NB; t += 256) {
            int h = sm.p.hist[t];
            int start = (h > 0) ? atomicAdd(&bucketCnt[t], h) : 0;
            sm.p.cur[t] = t * BCAP + start;
        }
        __syncthreads();
        #pragma unroll
        for (int it = 0; it < CHUNK / 256; ++it) {
            int i = base + it * 256 + tid;
            if (i < N_EDGES) {
                int r = row[i];
                int b = r >> 8;
                int p = atomicAdd(&sm.p.cur[b], 1);
                if (p < (b + 1) * BCAP) {
                    uint2 e;
                    e.x = __float_as_uint(ev[i]);
                    e.y = (uint)col[i] | ((uint)(r & 255) << 20);
                    es0[p] = e;
                } else {
                    int q = atomicAdd(ovfCnt, 1);
                    if (q < OVF_CAP) {
                        ovfRow[q] = r;
                        ovfCol[q] = col[i];
                        ovfVal[q] = ev[i];
                    }
                }
            }
        }
        __syncthreads();   // LDS reuse: p -> g
    }

    // ---------------- gemm role (all blocks) -----------------------------
    #pragma unroll
    for (int it = 0; it < 16; ++it) {
        int idx4 = tid + it * 256;        // 4096 float4 = 128x128
        int k = idx4 >> 5;
        int n0 = (idx4 & 31) * 4;
        float4 v = *(const float4*)(w + (size_t)idx4 * 4);
        float vv[4] = {v.x, v.y, v.z, v.w};
        #pragma unroll
        for (int q = 0; q < 4; ++q) {
            int n = n0 + q;
            sm.g.wt[n * 128 + (k ^ ((n & 7) << 3))] = f2bf(vv[q]);
        }
    }
    __syncthreads();

    const int lane = tid & 63;
    const int l15 = lane & 15;
    const int h = lane >> 4;
    const int wv = tid >> 6;
    ushort* yt = &sm.g.ytile[wv][0];

    short8 bfr[8][4];
    #pragma unroll
    for (int j = 0; j < 8; ++j) {
        int n = 16 * j + l15;
        #pragma unroll
        for (int ks = 0; ks < 4; ++ks) {
            int k0 = 32 * ks + 8 * h;
            bfr[j][ks] = *(const short8*)&sm.g.wt[n * 128 + (k0 ^ ((n & 7) << 3))];
        }
    }

    short8 a[4];
    int t;
    {
        if (lane == 0) t = atomicAdd(tick, 1);
        t = __shfl(t, 0);
        if (t < N_TILES) {
            const float* xr = x + (size_t)(t * 16 + l15) * D;
            float4 xb[8];
            #pragma unroll
            for (int ks = 0; ks < 4; ++ks) {
                xb[2 * ks]     = *(const float4*)(xr + 32 * ks + 8 * h);
                xb[2 * ks + 1] = *(const float4*)(xr + 32 * ks + 8 * h + 4);
            }
            #pragma unroll
            for (int ks = 0; ks < 4; ++ks) {
                const float* p0 = (const float*)&xb[2 * ks];
                const float* p1 = (const float*)&xb[2 * ks + 1];
                a[ks][0] = f2bf(p0[0]); a[ks][1] = f2bf(p0[1]);
                a[ks][2] = f2bf(p0[2]); a[ks][3] = f2bf(p0[3]);
                a[ks][4] = f2bf(p1[0]); a[ks][5] = f2bf(p1[1]);
                a[ks][6] = f2bf(p1[2]); a[ks][7] = f2bf(p1[3]);
            }
        }
    }
    #pragma unroll 1
    while (t < N_TILES) {
        int tn_;
        if (lane == 0) tn_ = atomicAdd(tick, 1);   // issue early; consume late

        f32x4 acc[8];
        #pragma unroll
        for (int j = 0; j < 8; ++j) acc[j] = (f32x4){0.f, 0.f, 0.f, 0.f};
        #pragma unroll
        for (int ks = 0; ks < 4; ++ks) {
            #pragma unroll
            for (int j = 0; j < 8; ++j)
                acc[j] = __builtin_amdgcn_mfma_f32_16x16x32_bf16(bfr[j][ks], a[ks], acc[j], 0, 0, 0);
        }
        // coalesced epilogue: stage 8B pieces in padded LDS, read back 16B/lane
        #pragma unroll
        for (int j = 0; j < 8; ++j) {
            us4 o;
            o.x = f2bf(acc[j][0]); o.y = f2bf(acc[j][1]);
            o.z = f2bf(acc[j][2]); o.w = f2bf(acc[j][3]);
            *(us4*)(yt + l15 * YT_P + 16 * j + 4 * h) = o;
        }
        ushort* yn = y + (size_t)(t * 16) * D;
        #pragma unroll
        for (int q = 0; q < 4; ++q) {
            int nl = 4 * q + h;
            float4 v = *(const float4*)(yt + nl * YT_P + l15 * 8);
            *(float4*)(yn + (size_t)nl * D + l15 * 8) = v;
        }

        int tn = __shfl(tn_, 0);   // atomic latency hidden under the MFMAs
        if (tn < N_TILES) {
            const float* xr = x + (size_t)(tn * 16 + l15) * D;
            float4 xb[8];
            #pragma unroll
            for (int ks = 0; ks < 4; ++ks) {
                xb[2 * ks]     = *(const float4*)(xr + 32 * ks + 8 * h);
                xb[2 * ks + 1] = *(const float4*)(xr + 32 * ks + 8 * h + 4);
            }
            #pragma unroll
            for (int ks = 0; ks < 4; ++ks) {
                const float* p0 = (const float*)&xb[2 * ks];
                const float* p1 = (const float*)&xb[2 * ks + 1];
                a[ks][0] = f2bf(p0[0]); a[ks][1] = f2bf(p0[1]);
                a[ks][2] = f2bf(p0[2]); a[ks][3] = f2bf(p0[3]);
                a[ks][4] = f2bf(p1[0]); a[ks][5] = f2bf(p1[1]);
                a[ks][6] = f2bf(p1[2]); a[ks][7] = f2bf(p1[3]);
            }
        }
        t = tn;
    }
}

// ---------------- build ELL in LDS, write coalesced ----------------
__global__ __launch_bounds__(256) void build_ell(const uint2* __restrict__ es0,
                                                 const int* __restrict__ bucketCnt,
                                                 float2* __restrict__ es,
                                                 int* __restrict__ counts,
                                                 int* __restrict__ ovfCnt,
                                                 int* __restrict__ ovfRow,
                                                 int* __restrict__ ovfCol,
                                                 float* __restrict__ ovfVal) {
    __shared__ float2 ell[256 * ELL_K];   // 32KB
    __shared__ int lcnt[256];
    const int tid = threadIdx.x;
    const int b = blockIdx.x;

    lcnt[tid] = 0;
    __syncthreads();

    int cnt = bucketCnt[b];
    if (cnt > BCAP) cnt = BCAP;
    const uint2* src = es0 + (size_t)b * BCAP;

    for (int i = tid; i < cnt; i += 256) {
        uint2 e = src[i];
        int r = e.y >> 20;
        int p = atomicAdd(&lcnt[r], 1);
        if (p < ELL_K) {
            float2 rec;
            rec.x = __uint_as_float(e.x);
            rec.y = __uint_as_float(e.y & 0xFFFFFu);
            ell[r * ELL_K + p] = rec;
        } else {
            int q = atomicAdd(ovfCnt, 1);
            if (q < OVF_CAP) {
                ovfRow[q] = b * 256 + r;
                ovfCol[q] = (int)(e.y & 0xFFFFFu);
                ovfVal[q] = __uint_as_float(e.x);
            }
        }
    }
    __syncthreads();

    const int nbase = b * 256;
    int nvalid = N_NODES - nbase;
    if (nvalid > 256) nvalid = 256;

    if (tid < nvalid) counts[nbase + tid] = lcnt[tid];

    float4* dst4 = (float4*)(es + (size_t)nbase * ELL_K);
    const float4* ell4 = (const float4*)ell;
    for (int t = tid; t < nvalid * (ELL_K / 2); t += 256)
        dst4[t] = ell4[t];
}

// ---------------- SpMM: 4 nodes per wave (16 lanes each), uint4 gathers ----
__global__ __launch_bounds__(256) void spmm_ell(const ushort* __restrict__ y,
                                                const float2* __restrict__ es,
                                                const int* __restrict__ counts,
                                                const float* __restrict__ bias,
                                                float* __restrict__ out) {
    const int tid = threadIdx.x;
    const int lane = tid & 63;
    const int c16 = lane & 15;       // channel group: ch c16*8 .. c16*8+7
    const int sub = lane >> 4;       // node sub-index 0..3
    const int wid = blockIdx.x * 4 + (tid >> 6);

    const float4 b0 = *(const float4*)(bias + c16 * 8);
    const float4 b1 = *(const float4*)(bias + c16 * 8 + 4);

    #pragma unroll 1
    for (int rep = 0; rep < 2; ++rep) {
        const int n = wid * 8 + rep * 4 + sub;
        int deg = counts[n];
        if (deg > ELL_K) deg = ELL_K;
        const float4* er = (const float4*)(es + (size_t)n * ELL_K);  // 8 float4

        float a0 = 0.f, a1 = 0.f, a2 = 0.f, a3 = 0.f;
        float a4 = 0.f, a5 = 0.f, a6 = 0.f, a7 = 0.f;

        #pragma unroll
        for (int g = 0; g < 4; ++g) {
            if (4 * g < deg) {
                float4 sA = er[2 * g];
                float4 sB = er[2 * g + 1];
                int c0 = __float_as_int(sA.y);
                int c1 = (4 * g + 1 < deg) ? __float_as_int(sA.w) : c0;
                int c2 = (4 * g + 2 < deg) ? __float_as_int(sB.y) : c0;
                int c3 = (4 * g + 3 < deg) ? __float_as_int(sB.w) : c0;
                uint4 u0 = *(const uint4*)(y + ((size_t)c0 << 7) + c16 * 8);
                uint4 u1 = *(const uint4*)(y + ((size_t)c1 << 7) + c16 * 8);
                uint4 u2 = *(const uint4*)(y + ((size_t)c2 << 7) + c16 * 8);
                uint4 u3 = *(const uint4*)(y + ((size_t)c3 << 7) + c16 * 8);
                float v0 = sA.x;
                float v1 = (4 * g + 1 < deg) ? sA.z : 0.f;
                float v2 = (4 * g + 2 < deg) ? sB.x : 0.f;
                float v3 = (4 * g + 3 < deg) ? sB.z : 0.f;
                a0 += v0 * bflo(u0.x); a1 += v0 * bfhi(u0.x);
                a2 += v0 * bflo(u0.y); a3 += v0 * bfhi(u0.y);
                a4 += v0 * bflo(u0.z); a5 += v0 * bfhi(u0.z);
                a6 += v0 * bflo(u0.w); a7 += v0 * bfhi(u0.w);
                a0 += v1 * bflo(u1.x); a1 += v1 * bfhi(u1.x);
                a2 += v1 * bflo(u1.y); a3 += v1 * bfhi(u1.y);
                a4 += v1 * bflo(u1.z); a5 += v1 * bfhi(u1.z);
                a6 += v1 * bflo(u1.w); a7 += v1 * bfhi(u1.w);
                a0 += v2 * bflo(u2.x); a1 += v2 * bfhi(u2.x);
                a2 += v2 * bflo(u2.y); a3 += v2 * bfhi(u2.y);
                a4 += v2 * bflo(u2.z); a5 += v2 * bfhi(u2.z);
                a6 += v2 * bflo(u2.w); a7 += v2 * bfhi(u2.w);
                a0 += v3 * bflo(u3.x); a1 += v3 * bfhi(u3.x);
                a2 += v3 * bflo(u3.y); a3 += v3 * bfhi(u3.y);
                a4 += v3 * bflo(u3.z); a5 += v3 * bfhi(u3.z);
                a6 += v3 * bflo(u3.w); a7 += v3 * bfhi(u3.w);
            }
        }
        float4 o0 = {a0 + b0.x, a1 + b0.y, a2 + b0.z, a3 + b0.w};
        float4 o1 = {a4 + b1.x, a5 + b1.y, a6 + b1.z, a7 + b1.w};
        float* orow = out + ((size_t)n << 7) + c16 * 8;
        *(float4*)orow = o0;
        *(float4*)(orow + 4) = o1;
    }
}

// ---------------- overflow fixup (rare) ----------------
__global__ void ovf_fix(const ushort* __restrict__ y, const int* __restrict__ ovfRow,
                        const int* __restrict__ ovfCol, const float* __restrict__ ovfVal,
                        const int* __restrict__ ovfCnt, float* __restrict__ out) {
    int nOvf = *ovfCnt;
    if (nOvf > OVF_CAP) nOvf = OVF_CAP;
    int total = nOvf * 32;
    for (int idx = blockIdx.x * 256 + threadIdx.x; idx < total; idx += gridDim.x * 256) {
        int e = idx >> 5;
        int c = idx & 31;
        int r = ovfRow[e];
        int col = ovfCol[e];
        float v = ovfVal[e];
        uint2 u = *(const uint2*)(y + ((size_t)col << 7) + c * 4);
        atomicAdd(&out[(size_t)r * D + c * 4 + 0], v * bflo(u.x));
        atomicAdd(&out[(size_t)r * D + c * 4 + 1], v * bfhi(u.x));
        atomicAdd(&out[(size_t)r * D + c * 4 + 2], v * bflo(u.y));
        atomicAdd(&out[(size_t)r * D + c * 4 + 3], v * bfhi(u.y));
    }
}

// ---------------- launch ----------------
extern "C" void kernel_launch(void* const* d_in, const int* in_sizes, int n_in,
                              void* d_out, int out_size, void* d_ws, size_t ws_size,
                              hipStream_t stream) {
    const float* x = (const float*)d_in[0];
    const float* w = (const float*)d_in[1];
    const float* bias = (const float*)d_in[2];
    const float* ev = (const float*)d_in[3];
    const int* row = (const int*)d_in[4];
    const int* col = (const int*)d_in[5];
    float* out = (float*)d_out;

    size_t off = 0;
    auto carve = [&](size_t bytes) -> void* {
        void* p = (char*)d_ws + off;
        off += (bytes + 255) & ~(size_t)255;
        return p;
    };
    ushort* y = (ushort*)carve((size_t)N_NODES * D * sizeof(ushort));
    int* counts = (int*)carve((size_t)N_NODES * sizeof(int));
    float2* es = (float2*)carve((size_t)N_NODES * ELL_K * sizeof(float2));
    uint2* es0 = (uint2*)carve((size_t)NB * BCAP * sizeof(uint2));
    int* ctrl = (int*)carve((2 + NB) * sizeof(int));   // tick, ovfCnt, bucketCnt[]
    int* ovfCnt = ctrl + 1;
    int* bucketCnt = ctrl + 2;
    int* ovfRow = (int*)carve(OVF_CAP * sizeof(int));
    int* ovfCol = (int*)carve(OVF_CAP * sizeof(int));
    float* ovfVal = (float*)carve(OVF_CAP * sizeof(float));

    hipMemsetAsync(ctrl, 0, (2 + NB) * sizeof(int), stream);
    gemm_part<<<GRID, 256, 0, stream>>>(x, w, y, ev, row, col, es0, ctrl,
                                        ovfRow, ovfCol, ovfVal);
    build_ell<<<NB, 256, 0, stream>>>(es0, bucketCnt, es, counts,
                                      ovfCnt, ovfRow, ovfCol, ovfVal);
    spmm_ell<<<N_NODES / 32, 256, 0, stream>>>(y, es, counts, bias, out);
    ovf_fix<<<16, 256, 0, stream>>>(y, ovfRow, ovfCol, ovfVal, ovfCnt, out);
}

// Round 16
// 87.448 us; speedup vs baseline: 1.9117x; 1.9117x over previous
//
#include <hip/hip_runtime.h>
#include <hip/hip_bf16.h>

// GCN layer: out = segment_sum(edge_val * (x@W)[col], row) + bias
// N=100000 nodes, E=640000 edges, D=128.
// y bf16. Pipeline (round-14 structure, best 83.7us): gemm (MFMA, NEW:
// LDS-resident B read per MFMA -> ~110 VGPR -> 3 blocks/CU, x prefetch,
// coalesced LDS-transpose epilogue) -> edge partition -> LDS-built ELL ->
// spmm (4 nodes/wave, uint4 gathers) -> overflow fixup.

#define N_NODES 100000
#define N_EDGES 640000
#define D 128
#define ELL_K 16
#define OVF_CAP 8192
#define NB 391          // ceil(N_NODES/256) row buckets
#define BCAP 2048       // per-bucket edge capacity (avg 1638)
#define CHUNK 4096
#define NCHUNKS 157     // ceil(N_EDGES/CHUNK)
#define N_TILES 6250
#define YT_P 132        // padded node-row stride in ushorts (banks spread)

typedef __attribute__((ext_vector_type(8))) short short8;
typedef __attribute__((ext_vector_type(4))) float f32x4;
typedef __attribute__((ext_vector_type(4))) ushort us4;

__device__ __forceinline__ ushort f2bf(float f) {
    __hip_bfloat16 h = __float2bfloat16(f);
    return __builtin_bit_cast(ushort, h);
}
__device__ __forceinline__ float bflo(uint u) { return __uint_as_float(u << 16); }
__device__ __forceinline__ float bfhi(uint u) { return __uint_as_float(u & 0xffff0000u); }

// ---------------- GEMM: y(bf16) = x @ W via MFMA 16x16x32 ----------------
// W^T staged once in LDS (XOR-swizzled). B-fragments read from LDS at each
// MFMA (asm memory clobber in the loop stops LICM from hoisting 128 VGPRs)
// -> ~110 VGPR -> 3 blocks/CU (launch_bounds(256,3), LDS 48.5KB), 12
// waves/CU of TLP. Swapped-operand mfma; coalesced epilogue via per-wave
// padded LDS tile; next tile's x loads prefetched. Also zeroes bucketCnt.
__global__ __launch_bounds__(256, 3) void gemm_xw(const float* __restrict__ x,
                                                  const float* __restrict__ w,
                                                  ushort* __restrict__ y,
                                                  int* __restrict__ bucketCnt) {
    __shared__ ushort wt[128 * 128];       // 32KB; idx = n*128 + (k ^ ((n&7)<<3))
    __shared__ ushort ytile[4][16 * YT_P]; // 16.5KB, per-wave C-tile staging
    const int tid = threadIdx.x;

    int gz = blockIdx.x * 256 + tid;
    if (gz <= NB) bucketCnt[gz] = 0;   // [NB] doubles as ovfCnt

    #pragma unroll
    for (int it = 0; it < 16; ++it) {
        int idx4 = tid + it * 256;        // 4096 float4 = 128x128
        int k = idx4 >> 5;
        int n0 = (idx4 & 31) * 4;
        float4 v = *(const float4*)(w + (size_t)idx4 * 4);
        float vv[4] = {v.x, v.y, v.z, v.w};
        #pragma unroll
        for (int q = 0; q < 4; ++q) {
            int n = n0 + q;
            wt[n * 128 + (k ^ ((n & 7) << 3))] = f2bf(vv[q]);
        }
    }
    __syncthreads();

    const int lane = tid & 63;
    const int l15 = lane & 15;
    const int h = lane >> 4;
    const int wv = tid >> 6;
    ushort* yt = &ytile[wv][0];

    const int waveGlobal = blockIdx.x * 4 + wv;
    const int nWaves = gridDim.x * 4;   // 3072

    int t = waveGlobal;
    if (t < N_TILES) {
        // prologue: load + convert tile t
        short8 a[4];
        {
            const float* xr = x + (size_t)(t * 16 + l15) * D;
            float4 xb[8];
            #pragma unroll
            for (int ks = 0; ks < 4; ++ks) {
                xb[2 * ks]     = *(const float4*)(xr + 32 * ks + 8 * h);
                xb[2 * ks + 1] = *(const float4*)(xr + 32 * ks + 8 * h + 4);
            }
            #pragma unroll
            for (int ks = 0; ks < 4; ++ks) {
                const float* p0 = (const float*)&xb[2 * ks];
                const float* p1 = (const float*)&xb[2 * ks + 1];
                a[ks][0] = f2bf(p0[0]); a[ks][1] = f2bf(p0[1]);
                a[ks][2] = f2bf(p0[2]); a[ks][3] = f2bf(p0[3]);
                a[ks][4] = f2bf(p1[0]); a[ks][5] = f2bf(p1[1]);
                a[ks][6] = f2bf(p1[2]); a[ks][7] = f2bf(p1[3]);
            }
        }
        #pragma unroll 1
        while (true) {
            const int tn = t + nWaves;
            const bool more = tn < N_TILES;
            asm volatile("" ::: "memory");   // keep B-frag LDS reads in-loop

            // issue next tile's loads early (hidden under MFMA + stores)
            float4 xb2[8];
            if (more) {
                const float* xr = x + (size_t)(tn * 16 + l15) * D;
                #pragma unroll
                for (int ks = 0; ks < 4; ++ks) {
                    xb2[2 * ks]     = *(const float4*)(xr + 32 * ks + 8 * h);
                    xb2[2 * ks + 1] = *(const float4*)(xr + 32 * ks + 8 * h + 4);
                }
            }

            f32x4 acc[8];
            #pragma unroll
            for (int j = 0; j < 8; ++j) acc[j] = (f32x4){0.f, 0.f, 0.f, 0.f};
            #pragma unroll
            for (int ks = 0; ks < 4; ++ks) {
                const int k0 = 32 * ks + 8 * h;
                #pragma unroll
                for (int j = 0; j < 8; ++j) {
                    int n = 16 * j + l15;
                    short8 b = *(const short8*)&wt[n * 128 + (k0 ^ ((n & 7) << 3))];
                    acc[j] = __builtin_amdgcn_mfma_f32_16x16x32_bf16(b, a[ks], acc[j], 0, 0, 0);
                }
            }

            // epilogue: stage 8B pieces in padded LDS, read back coalesced
            #pragma unroll
            for (int j = 0; j < 8; ++j) {
                us4 o;
                o.x = f2bf(acc[j][0]); o.y = f2bf(acc[j][1]);
                o.z = f2bf(acc[j][2]); o.w = f2bf(acc[j][3]);
                *(us4*)(yt + l15 * YT_P + 16 * j + 4 * h) = o;
            }
            ushort* yn = y + (size_t)(t * 16) * D;
            #pragma unroll
            for (int q = 0; q < 4; ++q) {
                int nl = 4 * q + h;          // local node 0..15
                float4 v = *(const float4*)(yt + nl * YT_P + l15 * 8);
                *(float4*)(yn + (size_t)nl * D + l15 * 8) = v;
            }

            if (!more) break;
            #pragma unroll
            for (int ks = 0; ks < 4; ++ks) {
                const float* p0 = (const float*)&xb2[2 * ks];
                const float* p1 = (const float*)&xb2[2 * ks + 1];
                a[ks][0] = f2bf(p0[0]); a[ks][1] = f2bf(p0[1]);
                a[ks][2] = f2bf(p0[2]); a[ks][3] = f2bf(p0[3]);
                a[ks][4] = f2bf(p1[0]); a[ks][5] = f2bf(p1[1]);
                a[ks][6] = f2bf(p1[2]); a[ks][7] = f2bf(p1[3]);
            }
            t = tn;
        }
    }
}

// ---------------- partition: edges -> 256-row buckets ----------------
__global__ __launch_bounds__(256) void partition_edges(const float* __restrict__ ev,
                                                       const int* __restrict__ row,
                                                       const int* __restrict__ col,
                                                       int* __restrict__ bucketCnt,
                                                       uint2* __restrict__ es0,
                                                       int* __restrict__ ovfCnt,
                                                       int* __restrict__ ovfRow,
                                                       int* __restrict__ ovfCol,
                                                       float* __restrict__ ovfVal) {
    __shared__ int hist[NB];
    __shared__ int cur[NB];
    const int tid = threadIdx.x;
    const int base = blockIdx.x * CHUNK;

    for (int t = tid; t < NB; t += 256) hist[t] = 0;
    __syncthreads();

    #pragma unroll
    for (int it = 0; it < CHUNK / 256; ++it) {
        int i = base + it * 256 + tid;
        if (i < N_EDGES) atomicAdd(&hist[row[i] >> 8], 1);
    }
    __syncthreads();

    for (int t = tid; t < NB; t += 256) {
        int h = hist[t];
        int start = (h > 0) ? atomicAdd(&bucketCnt[t], h) : 0;
        cur[t] = t * BCAP + start;
    }
    __syncthreads();

    #pragma unroll
    for (int it = 0; it < CHUNK / 256; ++it) {
        int i = base + it * 256 + tid;
        if (i < N_EDGES) {
            int r = row[i];
            int b = r >> 8;
            int p = atomicAdd(&cur[b], 1);
            if (p < (b + 1) * BCAP) {
                uint2 e;
                e.x = __float_as_uint(ev[i]);
                e.y = (uint)col[i] | ((uint)(r & 255) << 20);
                es0[p] = e;
            } else {
                int q = atomicAdd(ovfCnt, 1);
                if (q < OVF_CAP) {
                    ovfRow[q] = r;
                    ovfCol[q] = col[i];
                    ovfVal[q] = ev[i];
                }
            }
        }
    }
}

// ---------------- build ELL in LDS, write coalesced ----------------
__global__ __launch_bounds__(256) void build_ell(const uint2* __restrict__ es0,
                                                 const int* __restrict__ bucketCnt,
                                                 float2* __restrict__ es,
                                                 int* __restrict__ counts,
                                                 int* __restrict__ ovfCnt,
                                                 int* __restrict__ ovfRow,
                                                 int* __restrict__ ovfCol,
                                                 float* __restrict__ ovfVal) {
    __shared__ float2 ell[256 * ELL_K];   // 32KB
    __shared__ int lcnt[256];
    const int tid = threadIdx.x;
    const int b = blockIdx.x;

    lcnt[tid] = 0;
    __syncthreads();

    int cnt = bucketCnt[b];
    if (cnt > BCAP) cnt = BCAP;
    const uint2* src = es0 + (size_t)b * BCAP;

    for (int i = tid; i < cnt; i += 256) {
        uint2 e = src[i];
        int r = e.y >> 20;
        int p = atomicAdd(&lcnt[r], 1);
        if (p < ELL_K) {
            float2 rec;
            rec.x = __uint_as_float(e.x);
            rec.y = __uint_as_float(e.y & 0xFFFFFu);
            ell[r * ELL_K + p] = rec;
        } else {
            int q = atomicAdd(ovfCnt, 1);
            if (q < OVF_CAP) {
                ovfRow[q] = b * 256 + r;
                ovfCol[q] = (int)(e.y & 0xFFFFFu);
                ovfVal[q] = __uint_as_float(e.x);
            }
        }
    }
    __syncthreads();

    const int nbase = b * 256;
    int nvalid = N_NODES - nbase;
    if (nvalid > 256) nvalid = 256;

    if (tid < nvalid) counts[nbase + tid] = lcnt[tid];

    float4* dst4 = (float4*)(es + (size_t)nbase * ELL_K);
    const float4* ell4 = (const float4*)ell;
    for (int t = tid; t < nvalid * (ELL_K / 2); t += 256)
        dst4[t] = ell4[t];
}

// ---------------- SpMM: 4 nodes per wave (16 lanes each), uint4 gathers ----
__global__ __launch_bounds__(256) void spmm_ell(const ushort* __restrict__ y,
                                                const float2* __restrict__ es,
                                                const int* __restrict__ counts,
                                                const float* __restrict__ bias,
                                                float* __restrict__ out) {
    const int tid = threadIdx.x;
    const int lane = tid & 63;
    const int c16 = lane & 15;       // channel group: ch c16*8 .. c16*8+7
    const int sub = lane >> 4;       // node sub-index 0..3
    const int wid = blockIdx.x * 4 + (tid >> 6);

    const float4 b0 = *(const float4*)(bias + c16 * 8);
    const float4 b1 = *(const float4*)(bias + c16 * 8 + 4);

    #pragma unroll 1
    for (int rep = 0; rep < 2; ++rep) {
        const int n = wid * 8 + rep * 4 + sub;
        int deg = counts[n];
        if (deg > ELL_K) deg = ELL_K;
        const float4* er = (const float4*)(es + (size_t)n * ELL_K);  // 8 float4

        float a0 = 0.f, a1 = 0.f, a2 = 0.f, a3 = 0.f;
        float a4 = 0.f, a5 = 0.f, a6 = 0.f, a7 = 0.f;

        #pragma unroll
        for (int g = 0; g < 4; ++g) {
            if (4 * g < deg) {
                float4 sA = er[2 * g];
                float4 sB = er[2 * g + 1];
                int c0 = __float_as_int(sA.y);
                int c1 = (4 * g + 1 < deg) ? __float_as_int(sA.w) : c0;
                int c2 = (4 * g + 2 < deg) ? __float_as_int(sB.y) : c0;
                int c3 = (4 * g + 3 < deg) ? __float_as_int(sB.w) : c0;
                uint4 u0 = *(const uint4*)(y + ((size_t)c0 << 7) + c16 * 8);
                uint4 u1 = *(const uint4*)(y + ((size_t)c1 << 7) + c16 * 8);
                uint4 u2 = *(const uint4*)(y + ((size_t)c2 << 7) + c16 * 8);
                uint4 u3 = *(const uint4*)(y + ((size_t)c3 << 7) + c16 * 8);
                float v0 = sA.x;
                float v1 = (4 * g + 1 < deg) ? sA.z : 0.f;
                float v2 = (4 * g + 2 < deg) ? sB.x : 0.f;
                float v3 = (4 * g + 3 < deg) ? sB.z : 0.f;
                a0 += v0 * bflo(u0.x); a1 += v0 * bfhi(u0.x);
                a2 += v0 * bflo(u0.y); a3 += v0 * bfhi(u0.y);
                a4 += v0 * bflo(u0.z); a5 += v0 * bfhi(u0.z);
                a6 += v0 * bflo(u0.w); a7 += v0 * bfhi(u0.w);
                a0 += v1 * bflo(u1.x); a1 += v1 * bfhi(u1.x);
                a2 += v1 * bflo(u1.y); a3 += v1 * bfhi(u1.y);
                a4 += v1 * bflo(u1.z); a5 += v1 * bfhi(u1.z);
                a6 += v1 * bflo(u1.w); a7 += v1 * bfhi(u1.w);
                a0 += v2 * bflo(u2.x); a1 += v2 * bfhi(u2.x);
                a2 += v2 * bflo(u2.y); a3 += v2 * bfhi(u2.y);
                a4 += v2 * bflo(u2.z); a5 += v2 * bfhi(u2.z);
                a6 += v2 * bflo(u2.w); a7 += v2 * bfhi(u2.w);
                a0 += v3 * bflo(u3.x); a1 += v3 * bfhi(u3.x);
                a2 += v3 * bflo(u3.y); a3 += v3 * bfhi(u3.y);
                a4 += v3 * bflo(u3.z); a5 += v3 * bfhi(u3.z);
                a6 += v3 * bflo(u3.w); a7 += v3 * bfhi(u3.w);
            }
        }
        float4 o0 = {a0 + b0.x, a1 + b0.y, a2 + b0.z, a3 + b0.w};
        float4 o1 = {a4 + b1.x, a5 + b1.y, a6 + b1.z, a7 + b1.w};
        float* orow = out + ((size_t)n << 7) + c16 * 8;
        *(float4*)orow = o0;
        *(float4*)(orow + 4) = o1;
    }
}

// ---------------- overflow fixup (rare) ----------------
__global__ void ovf_fix(const ushort* __restrict__ y, const int* __restrict__ ovfRow,
                        const int* __restrict__ ovfCol, const float* __restrict__ ovfVal,
                        const int* __restrict__ ovfCnt, float* __restrict__ out) {
    int nOvf = *ovfCnt;
    if (nOvf > OVF_CAP) nOvf = OVF_CAP;
    int total = nOvf * 32;
    for (int idx = blockIdx.x * 256 + threadIdx.x; idx < total; idx += gridDim.x * 256) {
        int e = idx >> 5;
        int c = idx & 31;
        int r = ovfRow[e];
        int col = ovfCol[e];
        float v = ovfVal[e];
        uint2 u = *(const uint2*)(y + ((size_t)col << 7) + c * 4);
        atomicAdd(&out[(size_t)r * D + c * 4 + 0], v * bflo(u.x));
        atomicAdd(&out[(size_t)r * D + c * 4 + 1], v * bfhi(u.x));
        atomicAdd(&out[(size_t)r * D + c * 4 + 2], v * bflo(u.y));
        atomicAdd(&out[(size_t)r * D + c * 4 + 3], v * bfhi(u.y));
    }
}

// ---------------- launch ----------------
extern "C" void kernel_launch(void* const* d_in, const int* in_sizes, int n_in,
                              void* d_out, int out_size, void* d_ws, size_t ws_size,
                              hipStream_t stream) {
    const float* x = (const float*)d_in[0];
    const float* w = (const float*)d_in[1];
    const float* bias = (const float*)d_in[2];
    const float* ev = (const float*)d_in[3];
    const int* row = (const int*)d_in[4];
    const int* col = (const int*)d_in[5];
    float* out = (float*)d_out;

    size_t off = 0;
    auto carve = [&](size_t bytes) -> void* {
        void* p = (char*)d_ws + off;
        off += (bytes + 255) & ~(size_t)255;
        return p;
    };
    ushort* y = (ushort*)carve((size_t)N_NODES * D * sizeof(ushort));
    int* counts = (int*)carve((size_t)N_NODES * sizeof(int));
    float2* es = (float2*)carve((size_t)N_NODES * ELL_K * sizeof(float2));
    uint2* es0 = (uint2*)carve((size_t)NB * BCAP * sizeof(uint2));
    int* bucketCnt = (int*)carve((NB + 1) * sizeof(int));  // [NB] = ovfCnt
    int* ovfCnt = bucketCnt + NB;
    int* ovfRow = (int*)carve(OVF_CAP * sizeof(int));
    int* ovfCol = (int*)carve(OVF_CAP * sizeof(int));
    float* ovfVal = (float*)carve(OVF_CAP * sizeof(float));

    gemm_xw<<<768, 256, 0, stream>>>(x, w, y, bucketCnt);
    partition_edges<<<NCHUNKS, 256, 0, stream>>>(ev, row, col, bucketCnt, es0,
                                                 ovfCnt, ovfRow, ovfCol, ovfVal);
    build_ell<<<NB, 256, 0, stream>>>(es0, bucketCnt, es, counts,
                                      ovfCnt, ovfRow, ovfCol, ovfVal);
    spmm_ell<<<N_NODES / 32, 256, 0, stream>>>(y, es, counts, bias, out);
    ovf_fix<<<16, 256, 0, stream>>>(y, ovfRow, ovfCol, ovfVal, ovfCnt, out);
}

// Round 17
// 83.309 us; speedup vs baseline: 2.0067x; 1.0497x over previous
//
#include <hip/hip_runtime.h>
#include <hip/hip_bf16.h>

// GCN layer: out = segment_sum(edge_val * (x@W)[col], row) + bias
// N=100000 nodes, E=640000 edges, D=128.
// y bf16. Best-measured pipeline (round 14, 83.7us): gemm (MFMA, reg-B,
// x prefetch, coalesced LDS-transpose epilogue, 2 blk/CU) -> edge partition
// (256-row buckets) -> LDS-built ELL -> spmm (4 nodes/wave, uint4 gathers)
// -> overflow fixup.
//
// Ledger (measured): role-fusion/persistent/ticket variants catastrophically
// regress (cross-XCD atomic serialization); LDS-B @3blk/CU regresses (+3.7us);
// 1:1 build+spmm fusion regresses (+7us, gather parallelism loss). Keep this.

#define N_NODES 100000
#define N_EDGES 640000
#define D 128
#define ELL_K 16
#define OVF_CAP 8192
#define NB 391          // ceil(N_NODES/256) row buckets
#define BCAP 2048       // per-bucket edge capacity (avg 1638)
#define CHUNK 4096
#define NCHUNKS 157     // ceil(N_EDGES/CHUNK)
#define N_TILES 6250
#define YT_P 132        // padded node-row stride in ushorts (banks spread)

typedef __attribute__((ext_vector_type(8))) short short8;
typedef __attribute__((ext_vector_type(4))) float f32x4;
typedef __attribute__((ext_vector_type(4))) ushort us4;

__device__ __forceinline__ ushort f2bf(float f) {
    __hip_bfloat16 h = __float2bfloat16(f);
    return __builtin_bit_cast(ushort, h);
}
__device__ __forceinline__ float bflo(uint u) { return __uint_as_float(u << 16); }
__device__ __forceinline__ float bfhi(uint u) { return __uint_as_float(u & 0xffff0000u); }

// ---------------- GEMM: y(bf16) = x @ W via MFMA 16x16x32 ----------------
// W^T staged in LDS (XOR-swizzled), whole W in regs as 8x4 B-fragments.
// Swapped-operand mfma: D[channel][node]. Epilogue: fragmented us4 pieces go
// to a per-wave padded LDS tile (16 nodes x 132 ushorts), then read back
// 16B/lane and store 4x 1024B fully-coalesced dwordx4 per tile.
// Also zeroes bucketCnt/ovfCnt.
__global__ __launch_bounds__(256, 2) void gemm_xw(const float* __restrict__ x,
                                                  const float* __restrict__ w,
                                                  ushort* __restrict__ y,
                                                  int* __restrict__ bucketCnt) {
    __shared__ ushort wt[128 * 128];       // 32KB; idx = n*128 + (k ^ ((n&7)<<3))
    __shared__ ushort ytile[4][16 * YT_P]; // 16.5KB, per-wave C-tile staging
    const int tid = threadIdx.x;

    int gz = blockIdx.x * 256 + tid;
    if (gz <= NB) bucketCnt[gz] = 0;   // [NB] doubles as ovfCnt

    #pragma unroll
    for (int it = 0; it < 16; ++it) {
        int idx4 = tid + it * 256;        // 4096 float4 = 128x128
        int k = idx4 >> 5;
        int n0 = (idx4 & 31) * 4;
        float4 v = *(const float4*)(w + (size_t)idx4 * 4);
        float vv[4] = {v.x, v.y, v.z, v.w};
        #pragma unroll
        for (int q = 0; q < 4; ++q) {
            int n = n0 + q;
            wt[n * 128 + (k ^ ((n & 7) << 3))] = f2bf(vv[q]);
        }
    }
    __syncthreads();

    const int lane = tid & 63;
    const int l15 = lane & 15;
    const int h = lane >> 4;
    const int wv = tid >> 6;
    ushort* yt = &ytile[wv][0];

    short8 bfr[8][4];
    #pragma unroll
    for (int j = 0; j < 8; ++j) {
        int n = 16 * j + l15;
        #pragma unroll
        for (int ks = 0; ks < 4; ++ks) {
            int k0 = 32 * ks + 8 * h;
            bfr[j][ks] = *(const short8*)&wt[n * 128 + (k0 ^ ((n & 7) << 3))];
        }
    }

    const int waveGlobal = blockIdx.x * 4 + wv;
    const int nWaves = gridDim.x * 4;   // 2048

    int t = waveGlobal;
    if (t < N_TILES) {
        // prologue: load + convert tile t
        short8 a[4];
        {
            const float* xr = x + (size_t)(t * 16 + l15) * D;
            float4 xb[8];
            #pragma unroll
            for (int ks = 0; ks < 4; ++ks) {
                xb[2 * ks]     = *(const float4*)(xr + 32 * ks + 8 * h);
                xb[2 * ks + 1] = *(const float4*)(xr + 32 * ks + 8 * h + 4);
            }
            #pragma unroll
            for (int ks = 0; ks < 4; ++ks) {
                const float* p0 = (const float*)&xb[2 * ks];
                const float* p1 = (const float*)&xb[2 * ks + 1];
                a[ks][0] = f2bf(p0[0]); a[ks][1] = f2bf(p0[1]);
                a[ks][2] = f2bf(p0[2]); a[ks][3] = f2bf(p0[3]);
                a[ks][4] = f2bf(p1[0]); a[ks][5] = f2bf(p1[1]);
                a[ks][6] = f2bf(p1[2]); a[ks][7] = f2bf(p1[3]);
            }
        }
        #pragma unroll 1
        while (true) {
            const int tn = t + nWaves;
            const bool more = tn < N_TILES;

            // issue next tile's loads early (hidden under MFMA + stores)
            float4 xb2[8];
            if (more) {
                const float* xr = x + (size_t)(tn * 16 + l15) * D;
                #pragma unroll
                for (int ks = 0; ks < 4; ++ks) {
                    xb2[2 * ks]     = *(const float4*)(xr + 32 * ks + 8 * h);
                    xb2[2 * ks + 1] = *(const float4*)(xr + 32 * ks + 8 * h + 4);
                }
            }

            f32x4 acc[8];
            #pragma unroll
            for (int j = 0; j < 8; ++j) acc[j] = (f32x4){0.f, 0.f, 0.f, 0.f};
            #pragma unroll
            for (int ks = 0; ks < 4; ++ks) {
                #pragma unroll
                for (int j = 0; j < 8; ++j)
                    acc[j] = __builtin_amdgcn_mfma_f32_16x16x32_bf16(bfr[j][ks], a[ks], acc[j], 0, 0, 0);
            }

            // epilogue: node = t*16 + l15 holds channels 16j+4h+r ->
            // stage 8B pieces in padded LDS, read back coalesced.
            #pragma unroll
            for (int j = 0; j < 8; ++j) {
                us4 o;
                o.x = f2bf(acc[j][0]); o.y = f2bf(acc[j][1]);
                o.z = f2bf(acc[j][2]); o.w = f2bf(acc[j][3]);
                *(us4*)(yt + l15 * YT_P + 16 * j + 4 * h) = o;
            }
            // same-wave RAW: compiler inserts lgkmcnt wait; no barrier needed
            ushort* yn = y + (size_t)(t * 16) * D;
            #pragma unroll
            for (int q = 0; q < 4; ++q) {
                int nl = 4 * q + h;          // local node 0..15
                float4 v = *(const float4*)(yt + nl * YT_P + l15 * 8);
                *(float4*)(yn + (size_t)nl * D + l15 * 8) = v;
            }

            if (!more) break;
            #pragma unroll
            for (int ks = 0; ks < 4; ++ks) {
                const float* p0 = (const float*)&xb2[2 * ks];
                const float* p1 = (const float*)&xb2[2 * ks + 1];
                a[ks][0] = f2bf(p0[0]); a[ks][1] = f2bf(p0[1]);
                a[ks][2] = f2bf(p0[2]); a[ks][3] = f2bf(p0[3]);
                a[ks][4] = f2bf(p1[0]); a[ks][5] = f2bf(p1[1]);
                a[ks][6] = f2bf(p1[2]); a[ks][7] = f2bf(p1[3]);
            }
            t = tn;
        }
    }
}

// ---------------- partition: edges -> 256-row buckets ----------------
__global__ __launch_bounds__(256) void partition_edges(const float* __restrict__ ev,
                                                       const int* __restrict__ row,
                                                       const int* __restrict__ col,
                                                       int* __restrict__ bucketCnt,
                                                       uint2* __restrict__ es0,
                                                       int* __restrict__ ovfCnt,
                                                       int* __restrict__ ovfRow,
                                                       int* __restrict__ ovfCol,
                                                       float* __restrict__ ovfVal) {
    __shared__ int hist[NB];
    __shared__ int cur[NB];
    const int tid = threadIdx.x;
    const int base = blockIdx.x * CHUNK;

    for (int t = tid; t < NB; t += 256) hist[t] = 0;
    __syncthreads();

    #pragma unroll
    for (int it = 0; it < CHUNK / 256; ++it) {
        int i = base + it * 256 + tid;
        if (i < N_EDGES) atomicAdd(&hist[row[i] >> 8], 1);
    }
    __syncthreads();

    for (int t = tid; t < NB; t += 256) {
        int h = hist[t];
        int start = (h > 0) ? atomicAdd(&bucketCnt[t], h) : 0;
        cur[t] = t * BCAP + start;
    }
    __syncthreads();

    #pragma unroll
    for (int it = 0; it < CHUNK / 256; ++it) {
        int i = base + it * 256 + tid;
        if (i < N_EDGES) {
            int r = row[i];
            int b = r >> 8;
            int p = atomicAdd(&cur[b], 1);
            if (p < (b + 1) * BCAP) {
                uint2 e;
                e.x = __float_as_uint(ev[i]);
                e.y = (uint)col[i] | ((uint)(r & 255) << 20);
                es0[p] = e;
            } else {
                int q = atomicAdd(ovfCnt, 1);
                if (q < OVF_CAP) {
                    ovfRow[q] = r;
                    ovfCol[q] = col[i];
                    ovfVal[q] = ev[i];
                }
            }
        }
    }
}

// ---------------- build ELL in LDS, write coalesced ----------------
__global__ __launch_bounds__(256) void build_ell(const uint2* __restrict__ es0,
                                                 const int* __restrict__ bucketCnt,
                                                 float2* __restrict__ es,
                                                 int* __restrict__ counts,
                                                 int* __restrict__ ovfCnt,
                                                 int* __restrict__ ovfRow,
                                                 int* __restrict__ ovfCol,
                                                 float* __restrict__ ovfVal) {
    __shared__ float2 ell[256 * ELL_K];   // 32KB
    __shared__ int lcnt[256];
    const int tid = threadIdx.x;
    const int b = blockIdx.x;

    lcnt[tid] = 0;
    __syncthreads();

    int cnt = bucketCnt[b];
    if (cnt > BCAP) cnt = BCAP;
    const uint2* src = es0 + (size_t)b * BCAP;

    for (int i = tid; i < cnt; i += 256) {
        uint2 e = src[i];
        int r = e.y >> 20;
        int p = atomicAdd(&lcnt[r], 1);
        if (p < ELL_K) {
            float2 rec;
            rec.x = __uint_as_float(e.x);
            rec.y = __uint_as_float(e.y & 0xFFFFFu);
            ell[r * ELL_K + p] = rec;
        } else {
            int q = atomicAdd(ovfCnt, 1);
            if (q < OVF_CAP) {
                ovfRow[q] = b * 256 + r;
                ovfCol[q] = (int)(e.y & 0xFFFFFu);
                ovfVal[q] = __uint_as_float(e.x);
            }
        }
    }
    __syncthreads();

    const int nbase = b * 256;
    int nvalid = N_NODES - nbase;
    if (nvalid > 256) nvalid = 256;

    if (tid < nvalid) counts[nbase + tid] = lcnt[tid];

    float4* dst4 = (float4*)(es + (size_t)nbase * ELL_K);
    const float4* ell4 = (const float4*)ell;
    for (int t = tid; t < nvalid * (ELL_K / 2); t += 256)
        dst4[t] = ell4[t];
}

// ---------------- SpMM: 4 nodes per wave (16 lanes each), uint4 gathers ----
__global__ __launch_bounds__(256) void spmm_ell(const ushort* __restrict__ y,
                                                const float2* __restrict__ es,
                                                const int* __restrict__ counts,
                                                const float* __restrict__ bias,
                                                float* __restrict__ out) {
    const int tid = threadIdx.x;
    const int lane = tid & 63;
    const int c16 = lane & 15;       // channel group: ch c16*8 .. c16*8+7
    const int sub = lane >> 4;       // node sub-index 0..3
    const int wid = blockIdx.x * 4 + (tid >> 6);

    const float4 b0 = *(const float4*)(bias + c16 * 8);
    const float4 b1 = *(const float4*)(bias + c16 * 8 + 4);

    #pragma unroll 1
    for (int rep = 0; rep < 2; ++rep) {
        const int n = wid * 8 + rep * 4 + sub;
        int deg = counts[n];
        if (deg > ELL_K) deg = ELL_K;
        const float4* er = (const float4*)(es + (size_t)n * ELL_K);  // 8 float4

        float a0 = 0.f, a1 = 0.f, a2 = 0.f, a3 = 0.f;
        float a4 = 0.f, a5 = 0.f, a6 = 0.f, a7 = 0.f;

        #pragma unroll
        for (int g = 0; g < 4; ++g) {
            if (4 * g < deg) {
                float4 sA = er[2 * g];
                float4 sB = er[2 * g + 1];
                int c0 = __float_as_int(sA.y);
                int c1 = (4 * g + 1 < deg) ? __float_as_int(sA.w) : c0;
                int c2 = (4 * g + 2 < deg) ? __float_as_int(sB.y) : c0;
                int c3 = (4 * g + 3 < deg) ? __float_as_int(sB.w) : c0;
                uint4 u0 = *(const uint4*)(y + ((size_t)c0 << 7) + c16 * 8);
                uint4 u1 = *(const uint4*)(y + ((size_t)c1 << 7) + c16 * 8);
                uint4 u2 = *(const uint4*)(y + ((size_t)c2 << 7) + c16 * 8);
                uint4 u3 = *(const uint4*)(y + ((size_t)c3 << 7) + c16 * 8);
                float v0 = sA.x;
                float v1 = (4 * g + 1 < deg) ? sA.z : 0.f;
                float v2 = (4 * g + 2 < deg) ? sB.x : 0.f;
                float v3 = (4 * g + 3 < deg) ? sB.z : 0.f;
                a0 += v0 * bflo(u0.x); a1 += v0 * bfhi(u0.x);
                a2 += v0 * bflo(u0.y); a3 += v0 * bfhi(u0.y);
                a4 += v0 * bflo(u0.z); a5 += v0 * bfhi(u0.z);
                a6 += v0 * bflo(u0.w); a7 += v0 * bfhi(u0.w);
                a0 += v1 * bflo(u1.x); a1 += v1 * bfhi(u1.x);
                a2 += v1 * bflo(u1.y); a3 += v1 * bfhi(u1.y);
                a4 += v1 * bflo(u1.z); a5 += v1 * bfhi(u1.z);
                a6 += v1 * bflo(u1.w); a7 += v1 * bfhi(u1.w);
                a0 += v2 * bflo(u2.x); a1 += v2 * bfhi(u2.x);
                a2 += v2 * bflo(u2.y); a3 += v2 * bfhi(u2.y);
                a4 += v2 * bflo(u2.z); a5 += v2 * bfhi(u2.z);
                a6 += v2 * bflo(u2.w); a7 += v2 * bfhi(u2.w);
                a0 += v3 * bflo(u3.x); a1 += v3 * bfhi(u3.x);
                a2 += v3 * bflo(u3.y); a3 += v3 * bfhi(u3.y);
                a4 += v3 * bflo(u3.z); a5 += v3 * bfhi(u3.z);
                a6 += v3 * bflo(u3.w); a7 += v3 * bfhi(u3.w);
            }
        }
        float4 o0 = {a0 + b0.x, a1 + b0.y, a2 + b0.z, a3 + b0.w};
        float4 o1 = {a4 + b1.x, a5 + b1.y, a6 + b1.z, a7 + b1.w};
        float* orow = out + ((size_t)n << 7) + c16 * 8;
        *(float4*)orow = o0;
        *(float4*)(orow + 4) = o1;
    }
}

// ---------------- overflow fixup (rare) ----------------
__global__ void ovf_fix(const ushort* __restrict__ y, const int* __restrict__ ovfRow,
                        const int* __restrict__ ovfCol, const float* __restrict__ ovfVal,
                        const int* __restrict__ ovfCnt, float* __restrict__ out) {
    int nOvf = *ovfCnt;
    if (nOvf > OVF_CAP) nOvf = OVF_CAP;
    int total = nOvf * 32;
    for (int idx = blockIdx.x * 256 + threadIdx.x; idx < total; idx += gridDim.x * 256) {
        int e = idx >> 5;
        int c = idx & 31;
        int r = ovfRow[e];
        int col = ovfCol[e];
        float v = ovfVal[e];
        uint2 u = *(const uint2*)(y + ((size_t)col << 7) + c * 4);
        atomicAdd(&out[(size_t)r * D + c * 4 + 0], v * bflo(u.x));
        atomicAdd(&out[(size_t)r * D + c * 4 + 1], v * bfhi(u.x));
        atomicAdd(&out[(size_t)r * D + c * 4 + 2], v * bflo(u.y));
        atomicAdd(&out[(size_t)r * D + c * 4 + 3], v * bfhi(u.y));
    }
}

// ---------------- launch ----------------
extern "C" void kernel_launch(void* const* d_in, const int* in_sizes, int n_in,
                              void* d_out, int out_size, void* d_ws, size_t ws_size,
                              hipStream_t stream) {
    const float* x = (const float*)d_in[0];
    const float* w = (const float*)d_in[1];
    const float* bias = (const float*)d_in[2];
    const float* ev = (const float*)d_in[3];
    const int* row = (const int*)d_in[4];
    const int* col = (const int*)d_in[5];
    float* out = (float*)d_out;

    size_t off = 0;
    auto carve = [&](size_t bytes) -> void* {
        void* p = (char*)d_ws + off;
        off += (bytes + 255) & ~(size_t)255;
        return p;
    };
    ushort* y = (ushort*)carve((size_t)N_NODES * D * sizeof(ushort));
    int* counts = (int*)carve((size_t)N_NODES * sizeof(int));
    float2* es = (float2*)carve((size_t)N_NODES * ELL_K * sizeof(float2));
    uint2* es0 = (uint2*)carve((size_t)NB * BCAP * sizeof(uint2));
    int* bucketCnt = (int*)carve((NB + 1) * sizeof(int));  // [NB] = ovfCnt
    int* ovfCnt = bucketCnt + NB;
    int* ovfRow = (int*)carve(OVF_CAP * sizeof(int));
    int* ovfCol = (int*)carve(OVF_CAP * sizeof(int));
    float* ovfVal = (float*)carve(OVF_CAP * sizeof(float));

    gemm_xw<<<512, 256, 0, stream>>>(x, w, y, bucketCnt);
    partition_edges<<<NCHUNKS, 256, 0, stream>>>(ev, row, col, bucketCnt, es0,
                                                 ovfCnt, ovfRow, ovfCol, ovfVal);
    build_ell<<<NB, 256, 0, stream>>>(es0, bucketCnt, es, counts,
                                      ovfCnt, ovfRow, ovfCol, ovfVal);
    spmm_ell<<<N_NODES / 32, 256, 0, stream>>>(y, es, counts, bias, out);
    ovf_fix<<<16, 256, 0, stream>>>(y, ovfRow, ovfCol, ovfVal, ovfCnt, out);
}